// Round 11
// baseline (260.358 us; speedup 1.0000x reference)
//
#include <hip/hip_runtime.h>

// SpatialCoherenceLoss — R11: ABLATION round (within-probe A/B). Three
// variants of the R8 structure as separate dispatches in one launch:
//   V_full  <1,1,3>  : stage+compute x3 (re-stages; vs R9's stage-once 54.4us
//                      -> stage/iter = (V_full-54.4)/2). Writes real out.
//   V_stage <1,0,64> : staging x64, compute replaced by LDS checksum.
//   V_comp  <0,1,6>  : compute x6 from uninit LDS (scratch only).
// Decomposes the ~20-22us structure-independent residue that survived R2-R10.
// loss = mean_{i,j} exp(-100*||s_i-s_j||^2) * (sq_i + sq_j - 2<p_i,p_j>)

#define NPTS 8192
#define DIM  64
#define TILE 128
#define NT   (NPTS / TILE)              // 64 tiles
#define NSG  (NT / 2)                   // 32 super rows
#define NSUP (NSG * (NSG + 1) / 2)      // 528 blocks

typedef __attribute__((ext_vector_type(8))) short bf16x8;
typedef __attribute__((ext_vector_type(4))) float f32x4;
typedef __attribute__((ext_vector_type(4))) float fv4;
typedef __attribute__((ext_vector_type(4))) ushort usv4;

#define AS3(p) ((__attribute__((address_space(3))) void*)(p))
#define AS1(p) ((const __attribute__((address_space(1))) void*)(p))

__device__ __forceinline__ ushort f2bf(float x) {
    unsigned u = __builtin_bit_cast(unsigned, x);
    unsigned r = (u + 0x7fffu + ((u >> 16) & 1u)) >> 16;
    return (ushort)r;
}
__device__ __forceinline__ float bf2f(ushort b) {
    unsigned u = ((unsigned)b) << 16;
    return __builtin_bit_cast(float, u);
}

constexpr float kCoordScale = 12.0112244f;  // sqrt(100*log2(e))

__global__ void scl_prep_kernel(const float* __restrict__ pred,
                                const float* __restrict__ spat,
                                ushort* __restrict__ pbf,
                                float4* __restrict__ params,
                                unsigned* __restrict__ ctr) {
    int i = blockIdx.x * blockDim.x + threadIdx.x;
    if (i == 0) ctr[0] = 0u;
    const fv4* pr = (const fv4*)(pred + (size_t)i * DIM);
    usv4* po = (usv4*)(pbf + (size_t)i * DIM);
    float sq = 0.f;
    #pragma unroll
    for (int k = 0; k < DIM / 4; ++k) {
        fv4 v = __builtin_nontemporal_load(&pr[k]);
        usv4 o;
        o.x = f2bf(v.x); o.y = f2bf(v.y); o.z = f2bf(v.z); o.w = f2bf(v.w);
        float a = bf2f(o.x), b = bf2f(o.y), c = bf2f(o.z), d = bf2f(o.w);
        sq += a * a + b * b + c * c + d * d;
        __builtin_nontemporal_store(o, &po[k]);
    }
    fv4 pm;
    pm.x = sq;
    pm.y = spat[2 * i] * kCoordScale;
    pm.z = spat[2 * i + 1] * kCoordScale;
    pm.w = 0.f;
    __builtin_nontemporal_store(pm, (fv4*)&params[i]);
}

template <int DO_STAGE, int DO_COMPUTE, int NITER, int WRITE_OUT>
__launch_bounds__(256, 2)
__global__ void scl_var_kernel(const ushort* __restrict__ pbf,
                               const float4* __restrict__ params,
                               float* __restrict__ partial,
                               unsigned* __restrict__ ctr,
                               float* __restrict__ out) {
    __shared__ __align__(16) char smem[73728];
    __shared__ float red[4];
    __shared__ int lastflag;

    const int tid  = threadIdx.x;
    const int lane = tid & 63;
    const int wave = tid >> 6;
    const int fr = lane & 15;
    const int h  = lane >> 4;

    int t = blockIdx.x;
    int si = 0, base = 0;
    while (base + (NSG - si) <= t) { base += NSG - si; ++si; }
    const int sj = si + (t - base);
    const bool diag = (si == sj);
    const int tiles[4] = {2 * si, 2 * si + 1, 2 * sj, 2 * sj + 1};

    auto stageTile = [&](int slot) {
        const char* g = (const char*)(pbf + (size_t)tiles[slot] * TILE * DIM);
        #pragma unroll
        for (int s4 = 0; s4 < 4; ++s4) {
            unsigned L = (unsigned)tid * 16u + (unsigned)s4 * 4096u;
            unsigned row = L >> 7;
            unsigned src = (L & ~127u) | ((L & 127u) ^ ((row & 7u) << 4));
            unsigned dst = (unsigned)slot * 16384u + (unsigned)wave * 1024u +
                           (unsigned)s4 * 4096u;
            __builtin_amdgcn_global_load_lds(AS1(g + src), AS3(smem + dst), 16, 0, 0);
        }
    };

    auto computeItem = [&](int sa, int sb) -> float {
        const char* aB = smem + (unsigned)sa * 16384u;
        const char* bB = smem + (unsigned)sb * 16384u;
        const float4* pA = (const float4*)(smem + 65536u + (unsigned)sa * 2048u);
        const float4* pB = (const float4*)(smem + 65536u + (unsigned)sb * 2048u);

        bf16x8 afrag[2][2];
        #pragma unroll
        for (int rb = 0; rb < 2; ++rb)
            #pragma unroll
            for (int ks = 0; ks < 2; ++ks) {
                unsigned row = (unsigned)(wave * 32 + rb * 16 + fr);
                unsigned off = (unsigned)(ks * 64 + h * 16);
                afrag[rb][ks] =
                    *(const bf16x8*)(aB + row * 128u + (off ^ ((row & 7u) << 4)));
            }

        f32x4 acc[2][8];
        #pragma unroll
        for (int rb = 0; rb < 2; ++rb)
            #pragma unroll
            for (int cb = 0; cb < 8; ++cb)
                acc[rb][cb] = (f32x4){0.f, 0.f, 0.f, 0.f};

        #pragma unroll
        for (int cb = 0; cb < 8; ++cb) {
            unsigned rowB = (unsigned)(cb * 16 + fr);
            unsigned sw = (rowB & 7u) << 4;
            const char* bb = bB + rowB * 128u;
            bf16x8 b0 = *(const bf16x8*)(bb + (((unsigned)(h * 16)) ^ sw));
            bf16x8 b1 = *(const bf16x8*)(bb + (((unsigned)(64 + h * 16)) ^ sw));
            #pragma unroll
            for (int rb = 0; rb < 2; ++rb) {
                acc[rb][cb] = __builtin_amdgcn_mfma_f32_16x16x32_bf16(
                    afrag[rb][0], b0, acc[rb][cb], 0, 0, 0);
                acc[rb][cb] = __builtin_amdgcn_mfma_f32_16x16x32_bf16(
                    afrag[rb][1], b1, acc[rb][cb], 0, 0, 0);
            }
        }

        float rsq[2][4], rsx[2][4], rsy[2][4];
        #pragma unroll
        for (int rb = 0; rb < 2; ++rb)
            #pragma unroll
            for (int reg = 0; reg < 4; ++reg) {
                float4 rp = pA[wave * 32 + rb * 16 + h * 4 + reg];
                rsq[rb][reg] = rp.x; rsx[rb][reg] = rp.y; rsy[rb][reg] = rp.z;
            }

        float tl = 0.f;
        #pragma unroll
        for (int cb = 0; cb < 8; ++cb) {
            float4 cp = pB[cb * 16 + fr];
            #pragma unroll
            for (int rb = 0; rb < 2; ++rb)
                #pragma unroll
                for (int reg = 0; reg < 4; ++reg) {
                    float dot = acc[rb][cb][reg];
                    float dx = rsx[rb][reg] - cp.y;
                    float dy = rsy[rb][reg] - cp.z;
                    float nd2 = fmaf(-dx, dx, (-dy) * dy);
                    float w = __builtin_amdgcn_exp2f(nd2);
                    float pd = fmaf(-2.f, dot, rsq[rb][reg] + cp.x);
                    tl = fmaf(w, pd, tl);
                }
        }
        return tl;
    };

    const float* lds_f = (const float*)smem;
    float loss = 0.f, chk = 0.f;

    #pragma unroll 1
    for (int iter = 0; iter < NITER; ++iter) {
        __syncthreads();                 // prev-iter LDS readers done
        if (DO_STAGE) {
            stageTile(0);
            stageTile(2);
            {   // wave w stages params for slot w (2 x 1KB); per-lane source
                const char* gp = (const char*)(params + tiles[wave] * TILE);
                #pragma unroll
                for (int s2 = 0; s2 < 2; ++s2) {
                    unsigned so  = (unsigned)s2 * 1024u + (unsigned)lane * 16u;
                    unsigned dst = 65536u + (unsigned)wave * 2048u +
                                   (unsigned)s2 * 1024u;
                    __builtin_amdgcn_global_load_lds(AS1(gp + so), AS3(smem + dst),
                                                     16, 0, 0);
                }
            }
            stageTile(1);
            stageTile(3);
            asm volatile("s_waitcnt vmcnt(8)" ::: "memory");  // slots 0,2+params
        }
        __syncthreads();

        if (DO_COMPUTE) {
            float tl = computeItem(0, 2);
            loss += diag ? tl : 2.f * tl;
        } else {
            chk += lds_f[tid] + lds_f[8192 + tid];            // consume slots 0,2
        }

        if (DO_STAGE) asm volatile("s_waitcnt vmcnt(0)" ::: "memory");
        __syncthreads();

        if (DO_COMPUTE) {
            loss += 2.f * computeItem(0, 3);
            if (!diag) loss += 2.f * computeItem(1, 2);
            float tl = computeItem(1, 3);
            loss += diag ? tl : 2.f * tl;
        } else {
            chk += lds_f[4096 + tid] + lds_f[12288 + tid];    // consume slots 1,3
        }
    }

    float v = DO_COMPUTE ? loss : chk;
    #pragma unroll
    for (int off = 32; off > 0; off >>= 1)
        v += __shfl_down(v, off, 64);
    if (lane == 0) red[wave] = v;
    __syncthreads();
    if (tid == 0)
        partial[blockIdx.x] = (red[0] + red[1]) + (red[2] + red[3]);

    if (WRITE_OUT) {
        if (tid == 0) {
            __threadfence();
            unsigned old = atomicAdd(ctr, 1u);
            lastflag = (old == (unsigned)(NSUP - 1)) ? 1 : 0;
            if (lastflag) __threadfence();
        }
        __syncthreads();
        if (lastflag) {
            float s = 0.f;
            for (int idx = tid; idx < NSUP; idx += 256) s += partial[idx];
            #pragma unroll
            for (int off = 32; off > 0; off >>= 1)
                s += __shfl_down(s, off, 64);
            if (lane == 0) red[wave] = s;
            __syncthreads();
            if (tid == 0)
                out[0] = ((red[0] + red[1]) + (red[2] + red[3])) *
                         (1.0f / ((float)NITER * 8192.0f * 8192.0f));
        }
    }
}

extern "C" void kernel_launch(void* const* d_in, const int* in_sizes, int n_in,
                              void* d_out, int out_size, void* d_ws, size_t ws_size,
                              hipStream_t stream) {
    const float* pred = (const float*)d_in[0];
    const float* spat = (const float*)d_in[1];
    float* out = (float*)d_out;

    ushort*   pbf      = (ushort*)d_ws;                                    // 1 MB
    float4*   params   = (float4*)((char*)d_ws + (size_t)NPTS * DIM * 2);  // 128 KB
    float*    partialF = (float*)((char*)params + NPTS * sizeof(float4));
    float*    partialS = partialF + NSUP;
    float*    partialC = partialS + NSUP;
    unsigned* ctr      = (unsigned*)(partialC + ((NSUP + 3) & ~3));

    scl_prep_kernel<<<NPTS / 256, 256, 0, stream>>>(pred, spat, pbf, params, ctr);
    // V_full: reference + real output (stage+compute x3, re-staged each iter)
    scl_var_kernel<1, 1, 3, 1><<<NSUP, 256, 0, stream>>>(pbf, params, partialF, ctr, out);
    // V_stage: staging x64, checksum consumption only
    scl_var_kernel<1, 0, 64, 0><<<NSUP, 256, 0, stream>>>(pbf, params, partialS, ctr, out);
    // V_comp: compute x6 from uninitialized LDS (scratch only)
    scl_var_kernel<0, 1, 6, 0><<<NSUP, 256, 0, stream>>>(pbf, params, partialC, ctr, out);
}

// Round 12
// 38.746 us; speedup vs baseline: 6.7196x; 6.7196x over previous
//
#include <hip/hip_runtime.h>

// SpatialCoherenceLoss — R12: COMPACT-CODE round. Identical structure/math to
// R8 (528 super-blocks, 4-slot LDS, same staging + vmcnt schedule); the only
// change is code size: items rolled into one loop (1 computeItem copy), cb
// loop rolled, epilogue fused per-cb (acc 64->8 regs). Tests the icache-cold
// theory for the ~20us fixed cost (F tracks code size across R2-R11, not
// structure; R9's rolled pass-loop paid F once then 10.7us/pass hot).
// loss = mean_{i,j} exp(-100*||s_i-s_j||^2) * (sq_i + sq_j - 2<p_i,p_j>)

#define NPTS 8192
#define DIM  64
#define TILE 128
#define NT   (NPTS / TILE)              // 64 tiles
#define NSG  (NT / 2)                   // 32 super rows
#define NSUP (NSG * (NSG + 1) / 2)      // 528 blocks

typedef __attribute__((ext_vector_type(8))) short bf16x8;
typedef __attribute__((ext_vector_type(4))) float f32x4;
typedef __attribute__((ext_vector_type(4))) float fv4;
typedef __attribute__((ext_vector_type(4))) ushort usv4;

#define AS3(p) ((__attribute__((address_space(3))) void*)(p))
#define AS1(p) ((const __attribute__((address_space(1))) void*)(p))

__device__ __forceinline__ ushort f2bf(float x) {
    unsigned u = __builtin_bit_cast(unsigned, x);
    unsigned r = (u + 0x7fffu + ((u >> 16) & 1u)) >> 16;
    return (ushort)r;
}
__device__ __forceinline__ float bf2f(ushort b) {
    unsigned u = ((unsigned)b) << 16;
    return __builtin_bit_cast(float, u);
}

constexpr float kCoordScale = 12.0112244f;  // sqrt(100*log2(e))

__global__ void scl_prep_kernel(const float* __restrict__ pred,
                                const float* __restrict__ spat,
                                ushort* __restrict__ pbf,
                                float4* __restrict__ params,
                                unsigned* __restrict__ ctr) {
    int i = blockIdx.x * blockDim.x + threadIdx.x;
    if (i == 0) ctr[0] = 0u;
    const fv4* pr = (const fv4*)(pred + (size_t)i * DIM);
    usv4* po = (usv4*)(pbf + (size_t)i * DIM);
    float sq = 0.f;
    #pragma unroll
    for (int k = 0; k < DIM / 4; ++k) {
        fv4 v = __builtin_nontemporal_load(&pr[k]);
        usv4 o;
        o.x = f2bf(v.x); o.y = f2bf(v.y); o.z = f2bf(v.z); o.w = f2bf(v.w);
        float a = bf2f(o.x), b = bf2f(o.y), c = bf2f(o.z), d = bf2f(o.w);
        sq += a * a + b * b + c * c + d * d;
        __builtin_nontemporal_store(o, &po[k]);
    }
    fv4 pm;
    pm.x = sq;
    pm.y = spat[2 * i] * kCoordScale;
    pm.z = spat[2 * i + 1] * kCoordScale;
    pm.w = 0.f;
    __builtin_nontemporal_store(pm, (fv4*)&params[i]);
}

// LDS: 4 tile slots x 16KB @0, 4 param slots x 2KB @65536 -> 72.5KB, 2 blk/CU.
__launch_bounds__(256, 2)
__global__ void scl_mfma_kernel(const ushort* __restrict__ pbf,
                                const float4* __restrict__ params,
                                float* __restrict__ partial,
                                unsigned* __restrict__ ctr,
                                float* __restrict__ out) {
    __shared__ __align__(16) char smem[73728];
    __shared__ float red[4];
    __shared__ int lastflag;

    const int tid  = threadIdx.x;
    const int lane = tid & 63;
    const int wave = tid >> 6;
    const int fr = lane & 15;
    const int h  = lane >> 4;

    int t = blockIdx.x;
    int si = 0, base = 0;
    while (base + (NSG - si) <= t) { base += NSG - si; ++si; }
    const int sj = si + (t - base);
    const bool diag = (si == sj);
    const int tiles[4] = {2 * si, 2 * si + 1, 2 * sj, 2 * sj + 1};

    auto stageTile = [&](int slot) {
        const char* g = (const char*)(pbf + (size_t)tiles[slot] * TILE * DIM);
        #pragma unroll 1
        for (int s4 = 0; s4 < 4; ++s4) {
            unsigned L = (unsigned)tid * 16u + (unsigned)s4 * 4096u;
            unsigned row = L >> 7;
            unsigned src = (L & ~127u) | ((L & 127u) ^ ((row & 7u) << 4));
            unsigned dst = (unsigned)slot * 16384u + (unsigned)wave * 1024u +
                           (unsigned)s4 * 4096u;
            __builtin_amdgcn_global_load_lds(AS1(g + src), AS3(smem + dst), 16, 0, 0);
        }
    };

    // issue order: slots 0,2 (needed first), params, then 1,3
    stageTile(0);
    stageTile(2);
    {
        const char* gp = (const char*)(params + tiles[wave] * TILE);
        #pragma unroll 1
        for (int s2 = 0; s2 < 2; ++s2) {
            unsigned so  = (unsigned)s2 * 1024u + (unsigned)lane * 16u;
            unsigned dst = 65536u + (unsigned)wave * 2048u + (unsigned)s2 * 1024u;
            __builtin_amdgcn_global_load_lds(AS1(gp + so), AS3(smem + dst), 16, 0, 0);
        }
    }
    stageTile(1);
    stageTile(3);

    float loss = 0.f;
    asm volatile("s_waitcnt vmcnt(8)" ::: "memory");  // slots 0,2 + params
    __syncthreads();

    #pragma unroll 1
    for (int m = 0; m < 4; ++m) {                      // items (0,2)(0,3)(1,2)(1,3)
        if (m == 1) {
            asm volatile("s_waitcnt vmcnt(0)" ::: "memory");
            __syncthreads();
        }
        if (m == 2 && diag) continue;                  // transpose of m=1
        const int sa = m >> 1, sb = 2 + (m & 1);

        const char* aB = smem + (unsigned)sa * 16384u;
        const char* bB = smem + (unsigned)sb * 16384u;
        const float4* pA = (const float4*)(smem + 65536u + (unsigned)sa * 2048u);
        const float4* pB = (const float4*)(smem + 65536u + (unsigned)sb * 2048u);

        // A frags (named regs; compile-time indices only)
        const unsigned row0 = (unsigned)(wave * 32 + fr);
        const unsigned row1 = row0 + 16u;
        const unsigned sw0 = (row0 & 7u) << 4, sw1 = (row1 & 7u) << 4;
        bf16x8 af00 = *(const bf16x8*)(aB + row0 * 128u + (((unsigned)(h * 16)) ^ sw0));
        bf16x8 af01 = *(const bf16x8*)(aB + row0 * 128u + (((unsigned)(64 + h * 16)) ^ sw0));
        bf16x8 af10 = *(const bf16x8*)(aB + row1 * 128u + (((unsigned)(h * 16)) ^ sw1));
        bf16x8 af11 = *(const bf16x8*)(aB + row1 * 128u + (((unsigned)(64 + h * 16)) ^ sw1));

        float rsq0[4], rsx0[4], rsy0[4], rsq1[4], rsx1[4], rsy1[4];
        #pragma unroll
        for (int reg = 0; reg < 4; ++reg) {
            float4 rp = pA[wave * 32 + h * 4 + reg];
            rsq0[reg] = rp.x; rsx0[reg] = rp.y; rsy0[reg] = rp.z;
            float4 rq = pA[wave * 32 + 16 + h * 4 + reg];
            rsq1[reg] = rq.x; rsx1[reg] = rq.y; rsy1[reg] = rq.z;
        }

        float tl = 0.f;
        #pragma unroll 1
        for (int cb = 0; cb < 8; ++cb) {
            unsigned rowB = (unsigned)(cb * 16 + fr);
            unsigned sw = (rowB & 7u) << 4;
            const char* bb = bB + rowB * 128u;
            bf16x8 b0 = *(const bf16x8*)(bb + (((unsigned)(h * 16)) ^ sw));
            bf16x8 b1 = *(const bf16x8*)(bb + (((unsigned)(64 + h * 16)) ^ sw));
            f32x4 a0 = (f32x4){0.f, 0.f, 0.f, 0.f};
            f32x4 a1 = (f32x4){0.f, 0.f, 0.f, 0.f};
            a0 = __builtin_amdgcn_mfma_f32_16x16x32_bf16(af00, b0, a0, 0, 0, 0);
            a0 = __builtin_amdgcn_mfma_f32_16x16x32_bf16(af01, b1, a0, 0, 0, 0);
            a1 = __builtin_amdgcn_mfma_f32_16x16x32_bf16(af10, b0, a1, 0, 0, 0);
            a1 = __builtin_amdgcn_mfma_f32_16x16x32_bf16(af11, b1, a1, 0, 0, 0);

            float4 cp = pB[cb * 16 + fr];
            #pragma unroll
            for (int reg = 0; reg < 4; ++reg) {
                {
                    float dx = rsx0[reg] - cp.y;
                    float dy = rsy0[reg] - cp.z;
                    float nd2 = fmaf(-dx, dx, (-dy) * dy);
                    float w = __builtin_amdgcn_exp2f(nd2);
                    float pd = fmaf(-2.f, a0[reg], rsq0[reg] + cp.x);
                    tl = fmaf(w, pd, tl);
                }
                {
                    float dx = rsx1[reg] - cp.y;
                    float dy = rsy1[reg] - cp.z;
                    float nd2 = fmaf(-dx, dx, (-dy) * dy);
                    float w = __builtin_amdgcn_exp2f(nd2);
                    float pd = fmaf(-2.f, a1[reg], rsq1[reg] + cp.x);
                    tl = fmaf(w, pd, tl);
                }
            }
        }
        loss += (diag && (m == 0 || m == 3)) ? tl : 2.f * tl;
    }

    #pragma unroll
    for (int off = 32; off > 0; off >>= 1)
        loss += __shfl_down(loss, off, 64);
    if (lane == 0) red[wave] = loss;
    __syncthreads();
    if (tid == 0) {
        partial[blockIdx.x] = (red[0] + red[1]) + (red[2] + red[3]);
        __threadfence();
        unsigned old = atomicAdd(ctr, 1u);
        lastflag = (old == (unsigned)(NSUP - 1)) ? 1 : 0;
        if (lastflag) __threadfence();
    }
    __syncthreads();
    if (lastflag) {
        float s = 0.f;
        for (int idx = tid; idx < NSUP; idx += 256) s += partial[idx];
        #pragma unroll
        for (int off = 32; off > 0; off >>= 1)
            s += __shfl_down(s, off, 64);
        if (lane == 0) red[wave] = s;
        __syncthreads();
        if (tid == 0)
            out[0] = ((red[0] + red[1]) + (red[2] + red[3])) *
                     (1.0f / (8192.0f * 8192.0f));
    }
}

extern "C" void kernel_launch(void* const* d_in, const int* in_sizes, int n_in,
                              void* d_out, int out_size, void* d_ws, size_t ws_size,
                              hipStream_t stream) {
    const float* pred = (const float*)d_in[0];
    const float* spat = (const float*)d_in[1];
    float* out = (float*)d_out;

    ushort*   pbf     = (ushort*)d_ws;                                    // 1 MB
    float4*   params  = (float4*)((char*)d_ws + (size_t)NPTS * DIM * 2);  // 128 KB
    float*    partial = (float*)((char*)params + NPTS * sizeof(float4));  // 2.1 KB
    unsigned* ctr     = (unsigned*)(partial + ((NSUP + 3) & ~3));

    scl_prep_kernel<<<NPTS / 256, 256, 0, stream>>>(pred, spat, pbf, params, ctr);
    scl_mfma_kernel<<<NSUP, 256, 0, stream>>>(pbf, params, partial, ctr, out);
}